// Round 9
// baseline (241.510 us; speedup 1.0000x reference)
//
#include <hip/hip_runtime.h>
#include <math.h>
#include <stdint.h>

// 1D grayscale dilation (max-plus conv), K=11, halo=5, fp32.
// out[i] = max_j ( x[i-5+j] + h[j] ),  h[j] = -(j-5)^2 / (4*scale)
//
// R4 81.7 / R5 80.5 / R6 81.6 / R8 79.4 / R9 80.1 / R10 79.3 us:
//   six structures (LDS tile, shuffles, direct-VGPR, pinned, global_load_lds,
//   nt-stores), identical time. Killed theories: MLP-serialization (R9:
//   no VGPR dest, still flat), L3 eviction (R10: nt stores, flat).
//   Surviving common factor: READ DUTY CYCLE ~50%. Every version strictly
//   alternates acquire-phase (reads in flight) and consume-phase (zero
//   reads in flight). Copy ubench (6.29 TB/s) keeps loads in flight 100%
//   of the time; we deliver 3.35 TB/s ~ half. None of the six overlapped
//   tile t+1's global reads with tile t's compute.
// R11: minimum 2-phase pipeline (T3 recipe, zero-asm variant) -- container
//   failed twice, no counters. Line audit found no hang mechanism: all
//   barriers control-uniform; LDS-DMA+barrier+ds_read pattern identical to
//   verified R9; write-buffer p^1 never aliases read-buffer p; no raw asm.
// R11b (this): resubmit. Per block: 8 consecutive tiles, 2 LDS buffers.
//   Issue next tile's fire-and-forget global_load_lds BEFORE computing
//   current tile; the __syncthreads() AFTER compute drains them (loads had
//   the whole compute phase ~1 HBM-latency to land). Read duty -> ~100%.
//   LDS 2x16.4KB -> 4 blk/CU.

typedef float f32x4 __attribute__((ext_vector_type(4)));

#define BLOCK   256
#define QPT     4                      // output quads per thread
#define TILE_Q  (BLOCK * QPT)          // 1024 quads per tile
#define HALO_Q  2                      // staged halo quads each side
#define STAGE_Q (TILE_Q + 2 * HALO_Q)  // 1028 quads = 16448 B per buffer
#define TPB     8                      // consecutive tiles per block

// Direct global->LDS 16B load. LDS dest = wave-uniform base + lane*16 (HW);
// global src is per-lane. AS casts via uintptr (LDS aperture 4GiB-aligned).
__device__ __forceinline__ void gload_lds16(const f32x4* g, f32x4* l) {
    __builtin_amdgcn_global_load_lds(
        (const __attribute__((address_space(1))) uint32_t*)(uintptr_t)g,
        (__attribute__((address_space(3))) uint32_t*)(uintptr_t)l,
        16, 0, 0);
}

__global__ __launch_bounds__(BLOCK) void dilate1d_kernel(
    const f32x4* __restrict__ x4,
    const float* __restrict__ scale_p,
    f32x4*       __restrict__ out4,
    int n4,        // number of float4 elements in x / out
    int ntiles)    // ceil(n4 / TILE_Q)
{
    __shared__ f32x4 smem[2][STAGE_Q];

    const float NEG  = -INFINITY;
    const f32x4 NEG4 = {NEG, NEG, NEG, NEG};
    const int   wid  = threadIdx.x >> 6;         // wave id (uniform)

    // ---- stage tile into LDS buffer b: direct-to-LDS, fire-and-forget ----
    auto stage = [&](int b, int tile) {
        const int g0 = tile * TILE_Q - HALO_Q;
        const bool interior = (g0 >= 0) && (g0 + STAGE_Q <= n4);
        if (interior) {
#pragma unroll
            for (int t = 0; t < QPT; ++t) {
                gload_lds16(x4 + g0 + t * BLOCK + threadIdx.x,  // per-lane src
                            &smem[b][t * BLOCK + wid * 64]);    // uniform dst
            }
            if (threadIdx.x < 2 * HALO_Q) {                     // wave 0
                gload_lds16(x4 + g0 + TILE_Q + threadIdx.x,
                            &smem[b][TILE_Q]);                  // uniform dst
            }
        } else {
            // only the first tile of block 0 / last tile overall come here
#pragma unroll
            for (int t = 0; t <= QPT; ++t) {
                int idx = threadIdx.x + t * BLOCK;
                if (idx < STAGE_Q) {
                    int g = g0 + idx;
                    smem[b][idx] = (g >= 0 && g < n4) ? x4[g] : NEG4;
                }
            }
        }
    };

    // ---- structuring element: hp[d] = -d^2/(4s) ----
    const float r4s = 1.0f / (4.0f * scale_p[0]);
    const float hp1 = -1.0f  * r4s;
    const float hp2 = -4.0f  * r4s;
    const float hp3 = -9.0f  * r4s;
    const float hp4 = -16.0f * r4s;
    const float hp5 = -25.0f * r4s;

    const int t0   = blockIdx.x * TPB;           // first tile of this block
    const int tend = (t0 + TPB < ntiles) ? t0 + TPB : ntiles;
    if (t0 >= ntiles) return;                    // block-uniform

    // ---- 2-phase pipeline: stage(t+1) BEFORE compute(t); drain at sync ----
    stage(0, t0);
    __syncthreads();                             // prologue drain

    int p = 0;
    for (int tile = t0; tile < tend; ++tile) {
        if (tile + 1 < tend) stage(p ^ 1, tile + 1);   // fire-and-forget

        const int Q0 = tile * TILE_Q;
#pragma unroll
        for (int t = 0; t < QPT; ++t) {
            int idx = threadIdx.x + t * BLOCK;   // tile-local quad
            int q   = Q0 + idx;                  // global output quad
            if (q >= n4) break;

            // w[k] = x[4*q + k - 8], k = 0..19  (5 consecutive ds_read_b128)
            float w[20];
#pragma unroll
            for (int r = 0; r < 5; ++r) {
                f32x4 v = smem[p][idx + r];
                w[4 * r + 0] = v.x;
                w[4 * r + 1] = v.y;
                w[4 * r + 2] = v.z;
                w[4 * r + 3] = v.w;
            }

            f32x4 o;
#pragma unroll
            for (int i = 0; i < 4; ++i) {
                int c = 8 + i;                   // center of window in w
                float m = w[c];                  // hp[0] == 0
                m = fmaxf(m, hp1 + fmaxf(w[c - 1], w[c + 1]));
                m = fmaxf(m, hp2 + fmaxf(w[c - 2], w[c + 2]));
                m = fmaxf(m, hp3 + fmaxf(w[c - 3], w[c + 3]));
                m = fmaxf(m, hp4 + fmaxf(w[c - 4], w[c + 4]));
                m = fmaxf(m, hp5 + fmaxf(w[c - 5], w[c + 5]));
                o[i] = m;
            }
            __builtin_nontemporal_store(o, out4 + q);
        }

        if (tile + 1 < tend) {
            __syncthreads();   // vmcnt(0) lgkmcnt(0) + barrier:
            p ^= 1;            // next tile's loads landed; buf p reusable
        }
    }
}

extern "C" void kernel_launch(void* const* d_in, const int* in_sizes, int n_in,
                              void* d_out, int out_size, void* d_ws, size_t ws_size,
                              hipStream_t stream) {
    const float* x       = (const float*)d_in[0];
    const float* scale_p = (const float*)d_in[1];
    float*       out     = (float*)d_out;

    int n      = in_sizes[0];
    int n4     = n / 4;                          // n = 2^25 -> n4 = 2^23
    int ntiles = (n4 + TILE_Q - 1) / TILE_Q;     // 8192
    int blocks = (ntiles + TPB - 1) / TPB;       // 1024 -> 4 blocks/CU

    dilate1d_kernel<<<blocks, BLOCK, 0, stream>>>(
        (const f32x4*)x, scale_p, (f32x4*)out, n4, ntiles);
}